// Round 8
// baseline (324.580 us; speedup 1.0000x reference)
//
#include <hip/hip_runtime.h>
#include <math.h>

#define E_DIM 1024
#define D_DIM 1024
#define A_DIM 512
#define B_NUM 32
#define S_DIM 2048
#define M_DIM (B_NUM * S_DIM)  // 65536

typedef unsigned short ushort;
typedef short short8 __attribute__((ext_vector_type(8)));
typedef float f32x4 __attribute__((ext_vector_type(4)));
typedef unsigned short ushort4v __attribute__((ext_vector_type(4)));

typedef const void __attribute__((address_space(1))) cglobal_t;
typedef void __attribute__((address_space(3))) lds_t;

__device__ __forceinline__ void gload_lds16(const void* g, void* l) {
    __builtin_amdgcn_global_load_lds((cglobal_t*)g, (lds_t*)l, 16, 0, 0);
}

__device__ __forceinline__ ushort f2bf(float x) {
    unsigned u = __float_as_uint(x);
    u += 0x7FFF + ((u >> 16) & 1);  // round-to-nearest-even
    return (ushort)(u >> 16);
}

__device__ __forceinline__ unsigned cvt_pk_bf16(float lo, float hi) {
    unsigned r;
    asm("v_cvt_pk_bf16_f32 %0, %1, %2" : "=v"(r) : "v"(lo), "v"(hi));
    return r;
}

__device__ __forceinline__ float fast_tanh(float x) {
    const float e = __expf(2.0f * x);
    return 1.0f - 2.0f * __builtin_amdgcn_rcpf(e + 1.0f);
}

// ---------------- K0c: enc fp32 -> bf16 (one-time, BW-bound) ----------------
__global__ __launch_bounds__(256) void k0c_cvt_enc(
    const float* __restrict__ enc, ushort* __restrict__ ebf) {
    const size_t stride = (size_t)gridDim.x * 256;
    const size_t n8 = (size_t)M_DIM * E_DIM / 8;
    for (size_t i = (size_t)blockIdx.x * 256 + threadIdx.x; i < n8; i += stride) {
        const float4 a = *reinterpret_cast<const float4*>(enc + i * 8);
        const float4 b = *reinterpret_cast<const float4*>(enc + i * 8 + 4);
        *reinterpret_cast<int4*>(ebf + i * 8) =
            make_int4(cvt_pk_bf16(a.x, a.y), cvt_pk_bf16(a.z, a.w),
                      cvt_pk_bf16(b.x, b.y), cvt_pk_bf16(b.z, b.w));
    }
}

// ---------------- K0: dec2[b][a] = dot(dh[b,:], Wd[:,a]) + bd[a] + be[a] ----------------
__global__ __launch_bounds__(256) void k0_dec_energy(
    const float* __restrict__ dh, const float* __restrict__ Wd,
    const float* __restrict__ bd, const float* __restrict__ be,
    float* __restrict__ dec2) {
    __shared__ float sdh[D_DIM];
    const int b = blockIdx.y;
    const int t = threadIdx.x;
    for (int i = t; i < D_DIM; i += 256) sdh[i] = dh[b * D_DIM + i];
    __syncthreads();
    const int a = blockIdx.x * 256 + t;
    float acc = bd[a] + be[a];
#pragma unroll 8
    for (int e = 0; e < D_DIM; ++e) acc += sdh[e] * Wd[(size_t)e * A_DIM + a];
    dec2[b * A_DIM + a] = acc;
}

// ---------------- K0b: Wt[a][e] = bf16(We[e][a]) ----------------
__global__ __launch_bounds__(256) void k0b_cvt_we(
    const float* __restrict__ We, ushort* __restrict__ Wt) {
    const int n = blockIdx.x;
    const int k0 = threadIdx.x * 4;
    ushort4v v;
#pragma unroll
    for (int j = 0; j < 4; ++j) v[j] = f2bf(We[(size_t)(k0 + j) * A_DIM + n]);
    *reinterpret_cast<ushort4v*>(&Wt[(size_t)n * E_DIM + k0]) = v;
}

// ---------------- K1: A global->reg, B LDS double-buffered; 128x256, 4 waves ----------------
#define BM3 128
#define BN3 256
#define NT3 32  // K tiles of 32

__global__ __launch_bounds__(256, 2) void k1_mfma_areg(
    const ushort* __restrict__ ebf, const ushort* __restrict__ Wt,
    const float* __restrict__ dec2, const float* __restrict__ v_w,
    float* __restrict__ pscores) {
    __shared__ ushort Bsu[2 * 8192];  // two 16KB B buffers [256 rows][32 k]

    const int t = threadIdx.x;
    const int l = t & 63;
    const int w = t >> 6;   // 0..3 = wn (col-wave)
    const int fr = l & 15;
    const int kg = l >> 4;

    // XCD swizzle: nwg=1024, o = xcd*128 + chunk; x-tiles contiguous per XCD, ny pairs adjacent
    const int o = ((blockIdx.x & 7) << 7) | (blockIdx.x >> 3);
    const int x = o >> 1, ny = o & 1;
    const int row0 = x * BM3;
    const int n0 = ny * BN3;
    const int b = row0 >> 11;

    // ---- A: direct global->reg fragment base (lane-exact MFMA A-layout) ----
    const ushort* Abase = ebf + (size_t)(row0 + fr) * E_DIM + kg * 8;

#define LOAD_A(dst, ktv)                                                       \
    {                                                                          \
        _Pragma("unroll") for (int i = 0; i < 8; ++i)                          \
            dst[i] = *reinterpret_cast<const short8*>(                         \
                Abase + (size_t)i * 16 * E_DIM + (ktv) * 32);                  \
    }

    // ---- B staging: 4 gload_lds per wave per tile; pre-swizzled global source ----
    const ushort* BsrcQ[4];
#pragma unroll
    for (int q = 0; q < 4; ++q) {
        const int row = (w * 4 + q) * 16 + (l >> 2);
        const int c = (l & 3) ^ ((row >> 1) & 3);
        BsrcQ[q] = Wt + (size_t)(n0 + row) * E_DIM + c * 8;
    }

#define STAGE_B(cb, ktv)                                                       \
    {                                                                          \
        _Pragma("unroll") for (int q = 0; q < 4; ++q)                          \
            gload_lds16(BsrcQ[q] + (ktv) * 32,                                 \
                        Bsu + (cb) * 8192 + (w * 4 + q) * 512);                \
    }

    // ---- B LDS read base (swizzled, 2-way max) ----
    const int rB = w * 64 + fr;
    const int bbyte = rB * 64 + ((kg ^ ((rB >> 1) & 3)) * 16);

    f32x4 acc[8][4];
#pragma unroll
    for (int i = 0; i < 8; ++i)
#pragma unroll
        for (int j = 0; j < 4; ++j) acc[i][j] = (f32x4){0.f, 0.f, 0.f, 0.f};

    short8 aP[8], aN[8];

#define ITER(acur, anext, cb, ktv, PF)                                         \
    {                                                                          \
        if (PF) {                                                              \
            STAGE_B((cb) ^ 1, (ktv) + 1);                                      \
            LOAD_A(anext, (ktv) + 1);                                          \
        }                                                                      \
        short8 bf[4];                                                          \
        _Pragma("unroll") for (int j = 0; j < 4; ++j)                          \
            bf[j] = *reinterpret_cast<const short8*>(                          \
                (const char*)Bsu + (cb) * 16384 + bbyte + j * 1024);           \
        __builtin_amdgcn_s_setprio(1);                                         \
        _Pragma("unroll") for (int i = 0; i < 8; ++i)                          \
            _Pragma("unroll") for (int j = 0; j < 4; ++j)                      \
                acc[i][j] = __builtin_amdgcn_mfma_f32_16x16x32_bf16(           \
                    acur[i], bf[j], acc[i][j], 0, 0, 0);                       \
        __builtin_amdgcn_s_setprio(0);                                         \
        if (PF) {                                                              \
            asm volatile("s_waitcnt vmcnt(8)" ::: "memory");                   \
            __builtin_amdgcn_s_barrier();                                      \
        }                                                                      \
    }

    // prologue: stage buf0 (kt=0), load A(0); retire stage, keep A in flight
    STAGE_B(0, 0);
    LOAD_A(aP, 0);
    asm volatile("s_waitcnt vmcnt(8)" ::: "memory");
    __builtin_amdgcn_s_barrier();

#pragma unroll
    for (int kt = 0; kt < NT3 - 2; kt += 2) {
        ITER(aP, aN, 0, kt, true);
        ITER(aN, aP, 1, kt + 1, true);
    }
    ITER(aP, aN, 0, NT3 - 2, true);
    ITER(aN, aP, 1, NT3 - 1, false);

    // Epilogue: rowsum = sum over this wave's 64 cols of tanh(acc+dec2)*v_w
    float rowsum[8][4];
#pragma unroll
    for (int i = 0; i < 8; ++i)
#pragma unroll
        for (int r = 0; r < 4; ++r) rowsum[i][r] = 0.0f;

#pragma unroll
    for (int j = 0; j < 4; ++j) {
        const int ag = n0 + w * 64 + j * 16 + fr;
        const float bias = dec2[b * A_DIM + ag];
        const float vw = v_w[ag];
#pragma unroll
        for (int i = 0; i < 8; ++i)
#pragma unroll
            for (int r = 0; r < 4; ++r)
                rowsum[i][r] += fast_tanh(acc[i][j][r] + bias) * vw;
    }
#pragma unroll
    for (int m = 1; m < 16; m <<= 1)
#pragma unroll
        for (int i = 0; i < 8; ++i)
#pragma unroll
            for (int r = 0; r < 4; ++r)
                rowsum[i][r] += __shfl_xor(rowsum[i][r], m, 64);

    __syncthreads();  // all waves done reading Bs
    float* red = reinterpret_cast<float*>(Bsu);  // [128][4]
    if (fr == 0) {
#pragma unroll
        for (int i = 0; i < 8; ++i)
#pragma unroll
            for (int r = 0; r < 4; ++r)
                red[(i * 16 + kg * 4 + r) * 4 + w] = rowsum[i][r];
    }
    __syncthreads();
    if (t < BM3) {
        const float s = red[t * 4] + red[t * 4 + 1] + red[t * 4 + 2] + red[t * 4 + 3];
        pscores[(size_t)(row0 + t) * 2 + ny] = s;
    }
}

// ---------------- K1 fallback (fp32 reg-staged, small-ws path) ----------------
#define BM 128
#define BN 128
#define BK 32
#define PAD 40
__global__ __launch_bounds__(256, 2) void k1_mfma_reg(
    const float* __restrict__ enc, const ushort* __restrict__ Wt,
    const float* __restrict__ dec2, const float* __restrict__ v_w,
    float* __restrict__ pscores) {
    __shared__ ushort As[2][BM][PAD];
    __shared__ ushort Bs[2][BN][PAD];

    const int t = threadIdx.x;
    const int l = t & 63;
    const int w = t >> 6;
    const int wm = w >> 1, wn = w & 1;
    const int fr = l & 15;
    const int kg = l >> 4;

    const int o = ((blockIdx.x & 7) << 8) | (blockIdx.x >> 3);
    const int x = o >> 2, y = o & 3;
    const int row0 = x * BM;
    const int n0 = y * BN;
    const int b = row0 >> 11;

    const int srow = t >> 1;
    const int skh = (t & 1) * 16;

    const float* Ag = enc + (size_t)(row0 + srow) * E_DIM + skh;
    const ushort* Bg = Wt + (size_t)(n0 + srow) * E_DIM + skh;

    f32x4 acc[4][4];
#pragma unroll
    for (int i = 0; i < 4; ++i)
#pragma unroll
        for (int j = 0; j < 4; ++j) acc[i][j] = (f32x4){0.f, 0.f, 0.f, 0.f};

    float4 pa[4];
    int4 pb[2];

#define STAGE_LOAD(k0)                                              \
    {                                                               \
        pa[0] = *reinterpret_cast<const float4*>(Ag + (k0));        \
        pa[1] = *reinterpret_cast<const float4*>(Ag + (k0) + 4);    \
        pa[2] = *reinterpret_cast<const float4*>(Ag + (k0) + 8);    \
        pa[3] = *reinterpret_cast<const float4*>(Ag + (k0) + 12);   \
        pb[0] = *reinterpret_cast<const int4*>(Bg + (k0));          \
        pb[1] = *reinterpret_cast<const int4*>(Bg + (k0) + 8);      \
    }

#define STAGE_WRITE(buf)                                                  \
    {                                                                     \
        unsigned uu[8];                                                   \
        _Pragma("unroll") for (int q = 0; q < 4; ++q) {                   \
            uu[2 * q] = cvt_pk_bf16(pa[q].x, pa[q].y);                    \
            uu[2 * q + 1] = cvt_pk_bf16(pa[q].z, pa[q].w);                \
        }                                                                 \
        *reinterpret_cast<int4*>(&As[buf][srow][skh]) =                   \
            make_int4(uu[0], uu[1], uu[2], uu[3]);                        \
        *reinterpret_cast<int4*>(&As[buf][srow][skh + 8]) =               \
            make_int4(uu[4], uu[5], uu[6], uu[7]);                        \
        *reinterpret_cast<int4*>(&Bs[buf][srow][skh]) = pb[0];            \
        *reinterpret_cast<int4*>(&Bs[buf][srow][skh + 8]) = pb[1];        \
    }

    STAGE_LOAD(0);
    STAGE_WRITE(0);
    __syncthreads();

    for (int kt = 0; kt < E_DIM / BK; ++kt) {
        const int cur = kt & 1;
        if (kt < E_DIM / BK - 1) STAGE_LOAD((kt + 1) * BK);

        short8 af[4], bf[4];
#pragma unroll
        for (int i = 0; i < 4; ++i)
            af[i] = *reinterpret_cast<const short8*>(&As[cur][wm * 64 + i * 16 + fr][kg * 8]);
#pragma unroll
        for (int j = 0; j < 4; ++j)
            bf[j] = *reinterpret_cast<const short8*>(&Bs[cur][wn * 64 + j * 16 + fr][kg * 8]);
#pragma unroll
        for (int i = 0; i < 4; ++i)
#pragma unroll
            for (int j = 0; j < 4; ++j)
                acc[i][j] = __builtin_amdgcn_mfma_f32_16x16x32_bf16(af[i], bf[j], acc[i][j], 0, 0, 0);

        if (kt < E_DIM / BK - 1) STAGE_WRITE(cur ^ 1);
        __syncthreads();
    }

    float rowsum[4][4];
#pragma unroll
    for (int i = 0; i < 4; ++i)
#pragma unroll
        for (int r = 0; r < 4; ++r) rowsum[i][r] = 0.0f;
#pragma unroll
    for (int j = 0; j < 4; ++j) {
        const int ag = n0 + wn * 64 + j * 16 + fr;
        const float bias = dec2[b * A_DIM + ag];
        const float vw = v_w[ag];
#pragma unroll
        for (int i = 0; i < 4; ++i)
#pragma unroll
            for (int r = 0; r < 4; ++r)
                rowsum[i][r] += fast_tanh(acc[i][j][r] + bias) * vw;
    }
#pragma unroll
    for (int m = 1; m < 16; m <<= 1)
#pragma unroll
        for (int i = 0; i < 4; ++i)
#pragma unroll
            for (int r = 0; r < 4; ++r)
                rowsum[i][r] += __shfl_xor(rowsum[i][r], m, 64);

    __syncthreads();
    float* red = reinterpret_cast<float*>(&As[0][0][0]);
    if (fr == 0) {
#pragma unroll
        for (int i = 0; i < 4; ++i)
#pragma unroll
            for (int r = 0; r < 4; ++r)
                red[(wm * 64 + i * 16 + kg * 4 + r) * 2 + wn] = rowsum[i][r];
    }
    __syncthreads();
    if (t < BM)
        pscores[(size_t)(row0 + t) * 4 + y] = red[t * 2] + red[t * 2 + 1];
}

// ---------------- K2: softmax over S per batch (W column partials) ----------------
__global__ __launch_bounds__(256) void k2_softmax(
    const float* __restrict__ pscores, const float* __restrict__ v_b,
    float* __restrict__ attn_out, int W) {
    __shared__ float sc[S_DIM];
    __shared__ float red[8];
    const int b = blockIdx.x;
    const int t = threadIdx.x;
    const int wave = t >> 6, lane = t & 63;
    const float vb = v_b[0];

    float lmax = -1e30f;
    for (int s = t; s < S_DIM; s += 256) {
        float v = vb;
        for (int c = 0; c < W; ++c) v += pscores[(size_t)(b * S_DIM + s) * W + c];
        sc[s] = v;
        lmax = fmaxf(lmax, v);
    }
#pragma unroll
    for (int off = 32; off > 0; off >>= 1) lmax = fmaxf(lmax, __shfl_down(lmax, off, 64));
    if (lane == 0) red[wave] = lmax;
    __syncthreads();
    const float bmax = fmaxf(fmaxf(red[0], red[1]), fmaxf(red[2], red[3]));

    float lsum = 0.0f;
    for (int s = t; s < S_DIM; s += 256) {
        const float e = expf(sc[s] - bmax);
        sc[s] = e;
        lsum += e;
    }
#pragma unroll
    for (int off = 32; off > 0; off >>= 1) lsum += __shfl_down(lsum, off, 64);
    if (lane == 0) red[4 + wave] = lsum;
    __syncthreads();
    const float inv = 1.0f / (red[4] + red[5] + red[6] + red[7]);
    for (int s = t; s < S_DIM; s += 256) attn_out[b * S_DIM + s] = sc[s] * inv;
}

// ---------------- K3 (bf16): context partials ----------------
#define SC_CHUNK 128
#define N_SC (S_DIM / SC_CHUNK)  // 16
__global__ __launch_bounds__(128) void k3_ctx_bf16(
    const ushort* __restrict__ ebf, const float* __restrict__ attn,
    float* __restrict__ pctx) {
    const int b = blockIdx.y;
    const int scb = blockIdx.x;
    const int t = threadIdx.x;
    const int s0 = scb * SC_CHUNK;
    float acc[8];
#pragma unroll
    for (int j = 0; j < 8; ++j) acc[j] = 0.0f;
    const ushort* base = ebf + (size_t)(b * S_DIM + s0) * E_DIM + t * 8;
#pragma unroll 4
    for (int s = 0; s < SC_CHUNK; ++s) {
        const float wgt = attn[b * S_DIM + s0 + s];
        const int4 v = *reinterpret_cast<const int4*>(base + (size_t)s * E_DIM);
        const unsigned* u = reinterpret_cast<const unsigned*>(&v);
#pragma unroll
        for (int j = 0; j < 4; ++j) {
            acc[2 * j] += wgt * __uint_as_float(u[j] << 16);
            acc[2 * j + 1] += wgt * __uint_as_float(u[j] & 0xffff0000u);
        }
    }
    float* dst = &pctx[(size_t)(b * N_SC + scb) * E_DIM + t * 8];
    *reinterpret_cast<float4*>(dst) = make_float4(acc[0], acc[1], acc[2], acc[3]);
    *reinterpret_cast<float4*>(dst + 4) = make_float4(acc[4], acc[5], acc[6], acc[7]);
}

// ---------------- K3 fallback (fp32 enc) ----------------
__global__ __launch_bounds__(256) void k3_ctx_partial(
    const float* __restrict__ enc, const float* __restrict__ attn,
    float* __restrict__ pctx) {
    const int b = blockIdx.y;
    const int scb = blockIdx.x;
    const int t = threadIdx.x;
    const int s0 = scb * SC_CHUNK;
    float4 acc = {0.0f, 0.0f, 0.0f, 0.0f};
    const float4* encv =
        reinterpret_cast<const float4*>(enc + (size_t)(b * S_DIM + s0) * E_DIM);
#pragma unroll 4
    for (int s = 0; s < SC_CHUNK; ++s) {
        const float w = attn[b * S_DIM + s0 + s];
        const float4 v = encv[(size_t)s * (E_DIM / 4) + t];
        acc.x += w * v.x;
        acc.y += w * v.y;
        acc.z += w * v.z;
        acc.w += w * v.w;
    }
    *reinterpret_cast<float4*>(&pctx[(size_t)(b * N_SC + scb) * E_DIM + t * 4]) = acc;
}

// ---------------- K4: reduce context partials ----------------
__global__ __launch_bounds__(256) void k4_ctx_reduce(
    const float* __restrict__ pctx, float* __restrict__ ctx) {
    const int b = blockIdx.x;
    const int t = threadIdx.x;
    float4 acc = {0.0f, 0.0f, 0.0f, 0.0f};
#pragma unroll
    for (int s = 0; s < N_SC; ++s) {
        const float4 v = *reinterpret_cast<const float4*>(
            &pctx[(size_t)(b * N_SC + s) * E_DIM + t * 4]);
        acc.x += v.x;
        acc.y += v.y;
        acc.z += v.z;
        acc.w += v.w;
    }
    *reinterpret_cast<float4*>(&ctx[(size_t)b * E_DIM + t * 4]) = acc;
}

extern "C" void kernel_launch(void* const* d_in, const int* in_sizes, int n_in,
                              void* d_out, int out_size, void* d_ws, size_t ws_size,
                              hipStream_t stream) {
    (void)in_sizes; (void)n_in; (void)out_size;
    const float* enc = (const float*)d_in[0];
    const float* dh  = (const float*)d_in[1];
    const float* We  = (const float*)d_in[2];
    const float* be  = (const float*)d_in[3];
    const float* Wd  = (const float*)d_in[4];
    const float* bd  = (const float*)d_in[5];
    const float* vw  = (const float*)d_in[6];
    const float* vb  = (const float*)d_in[7];

    float* out = (float*)d_out;
    float* ctx_out = out;                   // [32,1024]
    float* attn_out = out + B_NUM * E_DIM;  // [32,2048]

    const size_t NEED = 138477568ULL;

    if (ws_size >= NEED) {
        char* W = (char*)d_ws;
        ushort* ebf    = (ushort*)W;                       // 134217728 B
        ushort* Wt     = (ushort*)(W + 134217728);         // 1048576 B
        float* dec2    = (float*)(W + 135266304);          // 65536 B
        float* pscores = (float*)(W + 135331840);          // 1MB region (uses 512KB)
        float* pctx    = (float*)(W + 136380416);          // 2097152 B

        k0c_cvt_enc<<<dim3(2048), 256, 0, stream>>>(enc, ebf);
        k0_dec_energy<<<dim3(2, 32), 256, 0, stream>>>(dh, Wd, bd, be, dec2);
        k0b_cvt_we<<<dim3(A_DIM), 256, 0, stream>>>(We, Wt);
        k1_mfma_areg<<<dim3((M_DIM / BM3) * (A_DIM / BN3)), 256, 0, stream>>>(
            ebf, Wt, dec2, vw, pscores);
        k2_softmax<<<dim3(B_NUM), 256, 0, stream>>>(pscores, vb, attn_out, 2);
        k3_ctx_bf16<<<dim3(N_SC, B_NUM), 128, 0, stream>>>(ebf, attn_out, pctx);
        k4_ctx_reduce<<<dim3(B_NUM), 256, 0, stream>>>(pctx, ctx_out);
    } else {
        float* ws = (float*)d_ws;
        float* dec2    = ws;
        float* pscores = ws + 16384;
        float* pctx    = ws + 16384 + 262144;
        ushort* Wt     = (ushort*)(ws + 16384 + 262144 + 524288);

        k0_dec_energy<<<dim3(2, 32), 256, 0, stream>>>(dh, Wd, bd, be, dec2);
        k0b_cvt_we<<<dim3(A_DIM), 256, 0, stream>>>(We, Wt);
        k1_mfma_reg<<<dim3((M_DIM / BM) * (A_DIM / BN)), 256, 0, stream>>>(
            enc, Wt, dec2, vw, pscores);
        k2_softmax<<<dim3(B_NUM), 256, 0, stream>>>(pscores, vb, attn_out, 4);
        k3_ctx_partial<<<dim3(N_SC, B_NUM), 256, 0, stream>>>(enc, attn_out, pctx);
        k4_ctx_reduce<<<dim3(B_NUM), 256, 0, stream>>>(pctx, ctx_out);
    }
}

// Round 9
// 221.028 us; speedup vs baseline: 1.4685x; 1.4685x over previous
//
#include <hip/hip_runtime.h>
#include <math.h>

#define E_DIM 1024
#define D_DIM 1024
#define A_DIM 512
#define B_NUM 32
#define S_DIM 2048
#define M_DIM (B_NUM * S_DIM)  // 65536

typedef unsigned short ushort;
typedef short short8 __attribute__((ext_vector_type(8)));
typedef float f32x4 __attribute__((ext_vector_type(4)));
typedef unsigned short ushort4v __attribute__((ext_vector_type(4)));

typedef const void __attribute__((address_space(1))) cglobal_t;
typedef void __attribute__((address_space(3))) lds_t;

__device__ __forceinline__ void gload_lds16(const void* g, void* l) {
    __builtin_amdgcn_global_load_lds((cglobal_t*)g, (lds_t*)l, 16, 0, 0);
}

__device__ __forceinline__ ushort f2bf(float x) {
    unsigned u = __float_as_uint(x);
    u += 0x7FFF + ((u >> 16) & 1);  // round-to-nearest-even
    return (ushort)(u >> 16);
}

__device__ __forceinline__ unsigned cvt_pk_bf16(float lo, float hi) {
    unsigned r;
    asm("v_cvt_pk_bf16_f32 %0, %1, %2" : "=v"(r) : "v"(lo), "v"(hi));
    return r;
}

__device__ __forceinline__ float fast_tanh(float x) {
    const float e = __expf(2.0f * x);
    return 1.0f - 2.0f * __builtin_amdgcn_rcpf(e + 1.0f);
}

// ---------------- K0: dec2[b][a] = dot(dh[b,:], Wd[:,a]) + bd[a] + be[a] ----------------
__global__ __launch_bounds__(256) void k0_dec_energy(
    const float* __restrict__ dh, const float* __restrict__ Wd,
    const float* __restrict__ bd, const float* __restrict__ be,
    float* __restrict__ dec2) {
    __shared__ float sdh[D_DIM];
    const int b = blockIdx.y;
    const int t = threadIdx.x;
    for (int i = t; i < D_DIM; i += 256) sdh[i] = dh[b * D_DIM + i];
    __syncthreads();
    const int a = blockIdx.x * 256 + t;
    float acc = bd[a] + be[a];
#pragma unroll 8
    for (int e = 0; e < D_DIM; ++e) acc += sdh[e] * Wd[(size_t)e * A_DIM + a];
    dec2[b * A_DIM + a] = acc;
}

// ---------------- K0b: Wt[a][e] = bf16(We[e][a]) ----------------
__global__ __launch_bounds__(256) void k0b_cvt_we(
    const float* __restrict__ We, ushort* __restrict__ Wt) {
    const int n = blockIdx.x;
    const int k0 = threadIdx.x * 4;
    ushort4v v;
#pragma unroll
    for (int j = 0; j < 4; ++j) v[j] = f2bf(We[(size_t)(k0 + j) * A_DIM + n]);
    *reinterpret_cast<ushort4v*>(&Wt[(size_t)n * E_DIM + k0]) = v;
}

// ---------------- K1: fused fp32->bf16 A-staging MFMA GEMM + tanh epilogue ----------------
// 128x256 tile, 4 waves (64x128 each), BK=32, double-buffered 48KB LDS, 2 blocks/CU.
#define BM4 128
#define BN4 256
#define NT4 32
#define BUFU4 12288  // ushorts per buffer: A 4096 (8KB) + B 8192 (16KB)

__global__ __launch_bounds__(256, 2) void k1_fused(
    const float* __restrict__ enc, const ushort* __restrict__ Wt,
    const float* __restrict__ dec2, const float* __restrict__ v_w,
    float* __restrict__ pscores) {
    __shared__ ushort L[2 * BUFU4];  // 48KB

    const int t = threadIdx.x;
    const int l = t & 63;
    const int w = t >> 6;            // 0..3
    const int wm = w >> 1, wn = w & 1;  // 2x2 wave grid; wave-tile 64x128
    const int fr = l & 15;
    const int kg = l >> 4;

    // XCD swizzle: nwg=1024 (div 8); ny-pairs adjacent (share A-tile in L2)
    const int o = ((blockIdx.x & 7) << 7) | (blockIdx.x >> 3);
    const int x = o >> 1, ny = o & 1;
    const int row0 = x * BM4;
    const int n0 = ny * BN4;
    const int b = row0 >> 11;

    // ---- A staging (fp32 global -> regs -> cvt -> swizzled LDS) ----
    // thread t: row = t>>1 (0..127), two logical 8-elem chunks c0=(t&1)*2, c0+1
    const int arow = t >> 1;
    const int ac0 = (t & 1) * 2;
    const float* Asrc = enc + (size_t)(row0 + arow) * E_DIM + ac0 * 8;  // 16 floats
    const int aswz0 = arow * 64 + ((ac0 ^ ((arow >> 1) & 3)) << 4);
    const int aswz1 = arow * 64 + (((ac0 + 1) ^ ((arow >> 1) & 3)) << 4);

    // ---- B staging (pre-swizzled global source -> gload_lds, linear dest) ----
    const ushort* BsrcQ[4];
#pragma unroll
    for (int q = 0; q < 4; ++q) {
        const int row = q * 64 + w * 16 + (l >> 2);
        const int c = (l & 3) ^ ((row >> 1) & 3);
        BsrcQ[q] = Wt + (size_t)(n0 + row) * E_DIM + c * 8;
    }

    f32x4 acc[4][8];
#pragma unroll
    for (int i = 0; i < 4; ++i)
#pragma unroll
        for (int j = 0; j < 8; ++j) acc[i][j] = (f32x4){0.f, 0.f, 0.f, 0.f};

    float4 pa[4];

#define LOADA4(ktv)                                                            \
    {                                                                          \
        pa[0] = *reinterpret_cast<const float4*>(Asrc + (ktv) * 32);           \
        pa[1] = *reinterpret_cast<const float4*>(Asrc + (ktv) * 32 + 4);       \
        pa[2] = *reinterpret_cast<const float4*>(Asrc + (ktv) * 32 + 8);       \
        pa[3] = *reinterpret_cast<const float4*>(Asrc + (ktv) * 32 + 12);      \
    }

#define STAGEB4(cb, ktv)                                                       \
    {                                                                          \
        _Pragma("unroll") for (int q = 0; q < 4; ++q)                          \
            gload_lds16(BsrcQ[q] + (ktv) * 32,                                 \
                        L + (cb) * BUFU4 + 4096 + (q * 64 + w * 16) * 32);     \
    }

#define WRITEA4(cb)                                                            \
    {                                                                          \
        const unsigned u0 = cvt_pk_bf16(pa[0].x, pa[0].y);                     \
        const unsigned u1 = cvt_pk_bf16(pa[0].z, pa[0].w);                     \
        const unsigned u2 = cvt_pk_bf16(pa[1].x, pa[1].y);                     \
        const unsigned u3 = cvt_pk_bf16(pa[1].z, pa[1].w);                     \
        const unsigned u4 = cvt_pk_bf16(pa[2].x, pa[2].y);                     \
        const unsigned u5 = cvt_pk_bf16(pa[2].z, pa[2].w);                     \
        const unsigned u6 = cvt_pk_bf16(pa[3].x, pa[3].y);                     \
        const unsigned u7 = cvt_pk_bf16(pa[3].z, pa[3].w);                     \
        *reinterpret_cast<int4*>((char*)L + (cb) * 24576 + aswz0) =            \
            make_int4(u0, u1, u2, u3);                                         \
        *reinterpret_cast<int4*>((char*)L + (cb) * 24576 + aswz1) =            \
            make_int4(u4, u5, u6, u7);                                         \
    }

    // prologue: A(0) regs + B(0) gload; retire A; write; sync
    LOADA4(0);
    STAGEB4(0, 0);
    asm volatile("s_waitcnt vmcnt(4)" ::: "memory");
    WRITEA4(0);
    __syncthreads();

    for (int kt = 0; kt < NT4; ++kt) {
        const int cur = kt & 1;
        if (kt < NT4 - 1) {
            LOADA4(kt + 1);           // A loads first (oldest)
            STAGEB4(cur ^ 1, kt + 1); // then B gloads
        }

        const char* Ab = (const char*)L + cur * 24576;
        const char* Bb = Ab + 8192;
        short8 af[4], bf[8];
#pragma unroll
        for (int i = 0; i < 4; ++i) {
            const int r = wm * 64 + i * 16 + fr;
            af[i] = *reinterpret_cast<const short8*>(
                Ab + r * 64 + ((kg ^ ((r >> 1) & 3)) << 4));
        }
#pragma unroll
        for (int j = 0; j < 8; ++j) {
            const int r = wn * 128 + j * 16 + fr;
            bf[j] = *reinterpret_cast<const short8*>(
                Bb + r * 64 + ((kg ^ ((r >> 1) & 3)) << 4));
        }
        __builtin_amdgcn_s_setprio(1);
#pragma unroll
        for (int i = 0; i < 4; ++i)
#pragma unroll
            for (int j = 0; j < 8; ++j)
                acc[i][j] = __builtin_amdgcn_mfma_f32_16x16x32_bf16(af[i], bf[j], acc[i][j], 0, 0, 0);
        __builtin_amdgcn_s_setprio(0);

        if (kt < NT4 - 1) {
            asm volatile("s_waitcnt vmcnt(4)" ::: "memory");  // A regs landed; B stays in flight
            WRITEA4(cur ^ 1);
        }
        __syncthreads();  // drains B gloads + LDS writes for next iter
    }

    // Epilogue: rowsum[i][r] = sum over this wave's 128 cols of tanh(acc+dec2)*v_w
    float rowsum[4][4];
#pragma unroll
    for (int i = 0; i < 4; ++i)
#pragma unroll
        for (int r = 0; r < 4; ++r) rowsum[i][r] = 0.0f;

#pragma unroll
    for (int j = 0; j < 8; ++j) {
        const int ag = n0 + wn * 128 + j * 16 + fr;
        const float bias = dec2[b * A_DIM + ag];
        const float vw = v_w[ag];
#pragma unroll
        for (int i = 0; i < 4; ++i)
#pragma unroll
            for (int r = 0; r < 4; ++r)
                rowsum[i][r] += fast_tanh(acc[i][j][r] + bias) * vw;
    }
#pragma unroll
    for (int m = 1; m < 16; m <<= 1)
#pragma unroll
        for (int i = 0; i < 4; ++i)
#pragma unroll
            for (int r = 0; r < 4; ++r)
                rowsum[i][r] += __shfl_xor(rowsum[i][r], m, 64);

    __syncthreads();
    float* red = reinterpret_cast<float*>(L);  // [128][2]
    if (fr == 0) {
#pragma unroll
        for (int i = 0; i < 4; ++i)
#pragma unroll
            for (int r = 0; r < 4; ++r)
                red[(wm * 64 + i * 16 + kg * 4 + r) * 2 + wn] = rowsum[i][r];
    }
    __syncthreads();
    if (t < BM4)
        pscores[(size_t)(row0 + t) * 2 + ny] = red[t * 2] + red[t * 2 + 1];
}

// ---------------- K2: softmax over S per batch (W column partials) ----------------
__global__ __launch_bounds__(256) void k2_softmax(
    const float* __restrict__ pscores, const float* __restrict__ v_b,
    float* __restrict__ attn_out, int W) {
    __shared__ float sc[S_DIM];
    __shared__ float red[8];
    const int b = blockIdx.x;
    const int t = threadIdx.x;
    const int wave = t >> 6, lane = t & 63;
    const float vb = v_b[0];

    float lmax = -1e30f;
    for (int s = t; s < S_DIM; s += 256) {
        float v = vb;
        for (int c = 0; c < W; ++c) v += pscores[(size_t)(b * S_DIM + s) * W + c];
        sc[s] = v;
        lmax = fmaxf(lmax, v);
    }
#pragma unroll
    for (int off = 32; off > 0; off >>= 1) lmax = fmaxf(lmax, __shfl_down(lmax, off, 64));
    if (lane == 0) red[wave] = lmax;
    __syncthreads();
    const float bmax = fmaxf(fmaxf(red[0], red[1]), fmaxf(red[2], red[3]));

    float lsum = 0.0f;
    for (int s = t; s < S_DIM; s += 256) {
        const float e = expf(sc[s] - bmax);
        sc[s] = e;
        lsum += e;
    }
#pragma unroll
    for (int off = 32; off > 0; off >>= 1) lsum += __shfl_down(lsum, off, 64);
    if (lane == 0) red[4 + wave] = lsum;
    __syncthreads();
    const float inv = 1.0f / (red[4] + red[5] + red[6] + red[7]);
    for (int s = t; s < S_DIM; s += 256) attn_out[b * S_DIM + s] = sc[s] * inv;
}

// ---------------- K3: context partials (fp32 enc; L3-resident after K1) ----------------
#define SC_CHUNK 128
#define N_SC (S_DIM / SC_CHUNK)  // 16
__global__ __launch_bounds__(256) void k3_ctx_partial(
    const float* __restrict__ enc, const float* __restrict__ attn,
    float* __restrict__ pctx) {
    const int b = blockIdx.y;
    const int scb = blockIdx.x;
    const int t = threadIdx.x;
    const int s0 = scb * SC_CHUNK;
    float4 acc = {0.0f, 0.0f, 0.0f, 0.0f};
    const float4* encv =
        reinterpret_cast<const float4*>(enc + (size_t)(b * S_DIM + s0) * E_DIM);
#pragma unroll 4
    for (int s = 0; s < SC_CHUNK; ++s) {
        const float w = attn[b * S_DIM + s0 + s];
        const float4 v = encv[(size_t)s * (E_DIM / 4) + t];
        acc.x += w * v.x;
        acc.y += w * v.y;
        acc.z += w * v.z;
        acc.w += w * v.w;
    }
    *reinterpret_cast<float4*>(&pctx[(size_t)(b * N_SC + scb) * E_DIM + t * 4]) = acc;
}

// ---------------- K4: reduce context partials ----------------
__global__ __launch_bounds__(256) void k4_ctx_reduce(
    const float* __restrict__ pctx, float* __restrict__ ctx) {
    const int b = blockIdx.x;
    const int t = threadIdx.x;
    float4 acc = {0.0f, 0.0f, 0.0f, 0.0f};
#pragma unroll
    for (int s = 0; s < N_SC; ++s) {
        const float4 v = *reinterpret_cast<const float4*>(
            &pctx[(size_t)(b * N_SC + s) * E_DIM + t * 4]);
        acc.x += v.x;
        acc.y += v.y;
        acc.z += v.z;
        acc.w += v.w;
    }
    *reinterpret_cast<float4*>(&ctx[(size_t)b * E_DIM + t * 4]) = acc;
}

extern "C" void kernel_launch(void* const* d_in, const int* in_sizes, int n_in,
                              void* d_out, int out_size, void* d_ws, size_t ws_size,
                              hipStream_t stream) {
    (void)in_sizes; (void)n_in; (void)out_size; (void)ws_size;
    const float* enc = (const float*)d_in[0];
    const float* dh  = (const float*)d_in[1];
    const float* We  = (const float*)d_in[2];
    const float* be  = (const float*)d_in[3];
    const float* Wd  = (const float*)d_in[4];
    const float* bd  = (const float*)d_in[5];
    const float* vw  = (const float*)d_in[6];
    const float* vb  = (const float*)d_in[7];

    float* out = (float*)d_out;
    float* ctx_out = out;                   // [32,1024]
    float* attn_out = out + B_NUM * E_DIM;  // [32,2048]

    float* ws = (float*)d_ws;
    float* dec2    = ws;                               // 16384 floats
    float* pscores = ws + 16384;                       // 131072 floats ([M][2])
    float* pctx    = ws + 16384 + 131072;              // 524288 floats
    ushort* Wt     = (ushort*)(ws + 16384 + 131072 + 524288);  // 1MB

    k0_dec_energy<<<dim3(2, 32), 256, 0, stream>>>(dh, Wd, bd, be, dec2);
    k0b_cvt_we<<<dim3(A_DIM), 256, 0, stream>>>(We, Wt);
    k1_fused<<<dim3((M_DIM / BM4) * (A_DIM / BN4)), 256, 0, stream>>>(
        enc, Wt, dec2, vw, pscores);
    k2_softmax<<<dim3(B_NUM), 256, 0, stream>>>(pscores, vb, attn_out, 2);
    k3_ctx_partial<<<dim3(N_SC, B_NUM), 256, 0, stream>>>(enc, attn_out, pctx);
    k4_ctx_reduce<<<dim3(B_NUM), 256, 0, stream>>>(pctx, ctx_out);
}